// Round 17
// baseline (97.060 us; speedup 1.0000x reference)
//
#include <hip/hip_runtime.h>
#include <math.h>

// Adder2D: out[n,co,h,w] = -sum_{ci,kh,kw} |x[n,ci,h+kh-1,w+kw-1] - w[co,ci,kh,kw]|
// x: [16,64,32,32] f32, w: [64,64,3,3] f32, out: [16,64,32,32] f32, pad=1 stride=1.
//
// R17: hand-scheduled A/B ci-pipeline. R16 post-mortem: VGPR=28 again --
// the allocator keeps collapsing pipeline depth to zero (can't even hold
// window+acc live), and the scheduler hoists next-ci loads above the
// current ci's forced lgkmcnt(0) (SMEM is OOO -> any wu use drains ALL
// lgkm ops, including just-issued next-ci ds_reads) -> ~200cy stall/ci in
// every variant. Fix by construction:
//   TAP0(A)  <- first tap touches wuA: compiler's lgkmcnt(0) lands HERE,
//               before B is issued; free if A prefetched a phase earlier
//   sched_barrier(0)
//   XL(B) WL(B)   <- 12 ds_read + s_load issued, no waits
//   sched_barrier(0)
//   REST(A)  <- 8 taps, 96 VALU, pure-register; covers B latency
// Named A/B arrays, compile-time indices only (rule #20); loads can't sink
// across sched_barrier -> values must stay live -> allocator forced to
// keep the pipeline. CG=4 (wuA+wuB = 72 SGPR fits; CG=8's 144 would not).
// Everything else = R15 (LW=35 conflict-free, s_load w, f2 packed core,
// 512thr / 4 cig / grid (4,16,16)).

#define N_   16
#define CI_  64
#define CO_  64
#define HW_  32
#define CG   4      // co per thread (= all of COB)
#define COB  4      // co per block
#define RG   8      // pixel rows per block
#define CIC  16     // ci planes staged per round
#define CPG  4      // ci planes computed per group per round
#define ROWS (RG + 2)
#define LW   35     // word0 = left halo, 1..32 = data, 33 = right halo, 34 pad
#define WSLICE 64   // floats per (cob,ci) w-slice slot (36 used, 256B aligned)

#define XS_WORDS (CIC * ROWS * LW)        // 5600 words = 22400 B

typedef __attribute__((ext_vector_type(2))) float f2;

// ---- repack: w[co][ci][t] -> wr[(co/4)*64+ci][ (co&3)*9 + t ], 64-f slots ----
__global__ void repack_w(const float* __restrict__ w, float* __restrict__ wr)
{
    int i  = blockIdx.x * 256 + threadIdx.x;   // 4096 = (co,ci) pairs
    int co = i >> 6;
    int ci = i & 63;
    float* dst = wr + (size_t)((co >> 2) * 64 + ci) * WSLICE + (co & 3) * 9;
    const float* src = w + (size_t)co * (CI_ * 9) + ci * 9;
#pragma unroll
    for (int t = 0; t < 9; ++t) dst[t] = src[t];
}

__global__ __launch_bounds__(512, 4) void adder2d_kernel(
    const float* __restrict__ x, const float* __restrict__ wr,
    float* __restrict__ out)
{
    __shared__ __align__(16) float smem[XS_WORDS];
    float (*xs)[ROWS][LW] = (float (*)[ROWS][LW])smem;   // phase A
    float (*red)[128][8]  = (float (*)[128][8])smem;     // phase B: aliases xs

    const int tid = threadIdx.x;
    const int u   = tid & 15;            // col-pair: pixels at cols 2u, 2u+1
    const int rl  = (tid >> 4) & 7;      // pixel row within block
    const int cig = tid >> 7;            // ci group: 0..3 (uniform per wave)
    const int r0  = blockIdx.x * RG;
    const int co0 = blockIdx.y * COB;
    const int n   = blockIdx.z;

    const int cigs = __builtin_amdgcn_readfirstlane(cig);
    const float* wrb = wr + (size_t)blockIdx.y * 64 * WSLICE;

    // ---- zero xs once: halo words (0,33) and OOB row slots stay zero ----
    for (int i = tid; i < XS_WORDS / 4; i += 512)
        ((float4*)smem)[i] = float4{0.f, 0.f, 0.f, 0.f};

    f2 acc2[CG];                         // .x = pixel col 2u, .y = col 2u+1
#pragma unroll
    for (int j = 0; j < CG; ++j) acc2[j] = f2{0.f, 0.f};

    const float* xn = x + (size_t)n * CI_ * HW_ * HW_;
    const int pbase = cig * CPG;

    float xA[12], xB[12];                // windows: [kh*4 + {a,b,c,d}]
    float wuA[36], wuB[36];              // w slices (SGPR-resident)

#define SB __builtin_amdgcn_sched_barrier(0)
#define XL(ARR, PL)                                                           \
    { _Pragma("unroll")                                                       \
      for (int kh = 0; kh < 3; ++kh) {                                        \
          const float* row = &xs[PL][rl + kh][2 * u];                         \
          ARR[kh * 4 + 0] = row[0]; ARR[kh * 4 + 1] = row[1];                 \
          ARR[kh * 4 + 2] = row[2]; ARR[kh * 4 + 3] = row[3];                 \
      } }
#define WL(ARR, CIS)                                                          \
    { const float* p = wrb + (size_t)(CIS) * WSLICE;                          \
      _Pragma("unroll")                                                       \
      for (int t = 0; t < 36; ++t) ARR[t] = p[t]; }
#define TAPC(ARR, WARR, KH, KW)                                               \
    { _Pragma("unroll")                                                       \
      for (int j = 0; j < CG; ++j) {                                          \
          const float wjt = WARR[j * 9 + (KH) * 3 + (KW)];                    \
          f2 xv = f2{ARR[(KH) * 4 + (KW)], ARR[(KH) * 4 + (KW) + 1]};         \
          f2 dv = xv - f2{wjt, wjt};                                          \
          acc2[j] += __builtin_elementwise_abs(dv);                           \
      } }
#define REST(ARR, WARR)                                                       \
    TAPC(ARR, WARR, 0, 1) TAPC(ARR, WARR, 0, 2)                               \
    TAPC(ARR, WARR, 1, 0) TAPC(ARR, WARR, 1, 1) TAPC(ARR, WARR, 1, 2)         \
    TAPC(ARR, WARR, 2, 0) TAPC(ARR, WARR, 2, 1) TAPC(ARR, WARR, 2, 2)

#pragma unroll 1
    for (int round = 0; round < CI_ / CIC; ++round) {
        const int cc0 = round * CIC;
        __syncthreads();   // protect LDS from previous round's readers
        // ---- stage CIC planes, rows r0-1..r0+8: 1280 float4 units ----
        for (int i = tid; i < CIC * ROWS * (HW_ / 4); i += 512) {
            int plane = i / (ROWS * (HW_ / 4));
            int rem   = i - plane * (ROWS * (HW_ / 4));
            int rr    = rem >> 3;
            int f4    = rem & 7;
            int gr    = r0 - 1 + rr;
            if ((unsigned)gr < HW_) {
                float4 v = ((const float4*)(xn + (size_t)(cc0 + plane) * HW_ * HW_
                                            + gr * HW_))[f4];
                float* dst = &xs[plane][rr][1 + 4 * f4];   // data words 1..32
                dst[0] = v.x; dst[1] = v.y; dst[2] = v.z; dst[3] = v.w;
            }
        }
        __syncthreads();

        const int cb = cc0 + cigs * CPG;

        // ---- hand-scheduled 4-ci pipeline (A/B alternating) ----
        XL(xA, pbase + 0) WL(wuA, cb + 0)            // prologue issues
        TAPC(xA, wuA, 0, 0) SB;                      // drain A (B not issued)
        XL(xB, pbase + 1) WL(wuB, cb + 1) SB;        // issue B, no waits
        REST(xA, wuA)                                // covers B latency

        TAPC(xB, wuB, 0, 0) SB;                      // drain B
        XL(xA, pbase + 2) WL(wuA, cb + 2) SB;        // issue A(+2)
        REST(xB, wuB)

        TAPC(xA, wuA, 0, 0) SB;                      // drain A
        XL(xB, pbase + 3) WL(wuB, cb + 3) SB;        // issue B(+3)
        REST(xA, wuA)

        TAPC(xB, wuB, 0, 0)                          // last ci: no prefetch
        REST(xB, wuB)
    }
#undef XL
#undef WL
#undef TAPC
#undef REST
#undef SB

    // ---- combine the four ci-group partials (red aliases dead xs) ----
    __syncthreads();   // all xs readers done before overwrite
    if (cig != 0) {
        int t = tid & 127;
        *(float4*)&red[cig - 1][t][0] =
            float4{acc2[0].x, acc2[1].x, acc2[2].x, acc2[3].x};
        *(float4*)&red[cig - 1][t][4] =
            float4{acc2[0].y, acc2[1].y, acc2[2].y, acc2[3].y};
    }
    __syncthreads();
    if (cig == 0) {
        float acc0[CG] = {acc2[0].x, acc2[1].x, acc2[2].x, acc2[3].x};
        float acc1[CG] = {acc2[0].y, acc2[1].y, acc2[2].y, acc2[3].y};
#pragma unroll
        for (int g = 0; g < 3; ++g) {
            float4 ra = *(const float4*)&red[g][tid][0];
            float4 rb = *(const float4*)&red[g][tid][4];
            acc0[0] += ra.x; acc0[1] += ra.y; acc0[2] += ra.z; acc0[3] += ra.w;
            acc1[0] += rb.x; acc1[1] += rb.y; acc1[2] += rb.z; acc1[3] += rb.w;
        }
        float* op = out + (((size_t)n * CO_ + co0) * HW_ + (r0 + rl)) * HW_ + 2 * u;
#pragma unroll
        for (int j = 0; j < CG; ++j)
            *(float2*)&op[(size_t)j * HW_ * HW_] = float2{-acc0[j], -acc1[j]};
    }
}

extern "C" void kernel_launch(void* const* d_in, const int* in_sizes, int n_in,
                              void* d_out, int out_size, void* d_ws, size_t ws_size,
                              hipStream_t stream) {
    const float* x  = (const float*)d_in[0];
    const float* wp = (const float*)d_in[1];
    float* out      = (float*)d_out;
    float* wr       = (float*)d_ws;   // 256 KiB (proven-safe footprint)

    repack_w<<<dim3(16), 256, 0, stream>>>(wp, wr);
    dim3 grid(HW_ / RG, CO_ / COB, N_);   // (4, 16, 16) = 1024 blocks
    adder2d_kernel<<<grid, 512, 0, stream>>>(x, wr, out);
}